// Round 5
// baseline (269.715 us; speedup 1.0000x reference)
//
#include <hip/hip_runtime.h>

#define T_LEN 1024
#define NS    128
#define BT    16
#define G     16
#define SEG   128        // time segments per sequence (power of 2)
#define SSH   7          // log2(SEG)
#define ST    8          // max rows per segment = T_LEN/SEG
#define NB    256        // total batches

typedef __attribute__((ext_vector_type(8))) short short8;
typedef __attribute__((ext_vector_type(4))) short short4v;
typedef __attribute__((ext_vector_type(4))) float f32x4;

static __device__ __forceinline__ short f2bf(float f) {   // RNE
    unsigned u = __builtin_bit_cast(unsigned, f);
    u = (u + 0x7fffu + ((u >> 16) & 1u)) >> 16;
    return (short)u;
}
static __device__ __forceinline__ float bf2f(short s) {
    unsigned u = ((unsigned)(unsigned short)s) << 16;
    return __builtin_bit_cast(float, u);
}
static __device__ __forceinline__ short f2bf_trunc(float f) {  // in-loop: 1 op
    return (short)(__builtin_bit_cast(unsigned, f) >> 16);
}

// Segmented CRF forward, MERGED fwd+bwd per block.  R1-R4 established the wall
// is DELIVERED BYTES (~3 TB/s for this mix, invariant to structure): unary was
// demanded twice (fwd units + bwd units).  Now ONE single-wave block per
// (s,g) runs the fwd sweep over segment s (global loads, per-batch-clamped so
// each row is fetched once), staging eu=exp(u) as RNE-bf16 into a 32KB LDS ring,
// then runs the bwd sweep over the SAME segment reading eu from LDS — zero
// global loads in bwd.  Demand halves (~67MB unique).  SEG 64->128 (ST=8) keeps
// LDS at 36KB -> 4 blocks/CU, 2048 blocks all-resident in 2 generations.
// Layout formulas (Fs swizzle, bfOff/fwo/s4Off, record semantics) verbatim from
// the R3/R4-verified kernel; EU slots use the same XOR family: slot=(chunk^b)&15.
__global__ __launch_bounds__(64, 1) void crf_seg(
        const float* __restrict__ unary, const float* __restrict__ trans,
        const int* __restrict__ lengths,
        float* __restrict__ yv, float* __restrict__ zv,
        float* __restrict__ cfv, float* __restrict__ cbv) {
    __shared__ __align__(16) short Fs[BT * NS];        // 4KB bf16 state
    __shared__ __align__(16) short EU[ST * BT * NS];   // 32KB bf16 eu ring

    const int tid = threadIdx.x;                  // 0..63 (one wave)
    const int g = blockIdx.x & (G - 1);
    const int s = blockIdx.x >> 4;                // 0..SEG-1
    const int quad = tid >> 4, bcol = tid & 15;

    // ---- per-batch segment bounds ----
    const int Lb = lengths[g * BT + bcol];
    const int tb = (s * Lb) >> SSH, te = ((s + 1) * Lb) >> SSH;
    const int slen = te - tb;
    const int nrec = slen - 1;                    // -1 => record happens at init
    int dlen = slen;
    #pragma unroll
    for (int m = 1; m < 16; m <<= 1) {            // max over the 16 batches
        int o = __shfl_xor(dlen, m, 64);
        dlen = o > dlen ? o : dlen;
    }
    const int iters = dlen;                       // <= ST

    // ---- A-fragments: E (fwd), 8 m-tiles x 4 k-tiles ----
    short8 Ea[8][4];
    #pragma unroll
    for (int j = 0; j < 8; ++j) {
        const int i = j * 16 + bcol;              // A's m-row
        #pragma unroll
        for (int kt = 0; kt < 4; ++kt) {
            const float* tr = trans + (size_t)i * NS + kt * 32 + quad * 8;
            float4 x = *(const float4*)tr, y = *(const float4*)(tr + 4);
            short8 e;
            e[0] = f2bf(__expf(x.x)); e[1] = f2bf(__expf(x.y));
            e[2] = f2bf(__expf(x.z)); e[3] = f2bf(__expf(x.w));
            e[4] = f2bf(__expf(y.x)); e[5] = f2bf(__expf(y.y));
            e[6] = f2bf(__expf(y.z)); e[7] = f2bf(__expf(y.w));
            Ea[j][kt] = e;
        }
    }

    // ---- fwd init state into Fs + fwd empty-segment records ----
    #pragma unroll
    for (int rep = 0; rep < 4; ++rep) {           // 4 reps x 64 lanes = 16x16 tile
        const int tv = rep * 64 + tid;
        const int sr = tv >> 4, sc = tv & 15;
        const int Ls = lengths[g * BT + sr];
        const int s_tb = (s * Ls) >> SSH, s_te = ((s + 1) * Ls) >> SSH;
        float v[8];
        #pragma unroll
        for (int k = 0; k < 8; ++k)
            v[k] = (s == 0) ? ((sc * 8 + k == 1) ? 1.f : 0.f) : 1.f;
        short8 z;
        #pragma unroll
        for (int k = 0; k < 8; ++k) z[k] = f2bf(v[k]);
        *(short8*)&Fs[sr * NS + ((sc ^ sr) << 3)] = z;

        if (s_te == s_tb && s < SEG - 1) {        // empty: record fwd seed
            float* yp = yv + ((size_t)s * NB + g * BT + sr) * NS + sc * 8;
            #pragma unroll
            for (int k = 0; k < 8; ++k)
                yp[k] = (s == 0) ? ((sc * 8 + k == 1) ? 1.f : 0.f) : 1.f;
            if (sc == 0) cfv[s * NB + g * BT + sr] = 0.f;
        }
    }

    // ---- per-lane unary pointer: batch bcol, rows j*16 + quad*4 ----
    const float* uptr = unary + (size_t)(g * BT + bcol) * T_LEN * NS + quad * 4;
    const int slenc = slen > 0 ? slen - 1 : 0;
    #define T_F(nn) (tb + ((nn) < slen ? (nn) : slenc))   // own-row clamp: no fresh overshoot lines
    float4 pA[8], pB[8];                          // 2-deep prefetch
    {
        int t = T_F(0);
        #pragma unroll
        for (int j = 0; j < 8; ++j) pA[j] = *(const float4*)(uptr + (size_t)t * NS + j * 16);
        t = T_F(1);
        #pragma unroll
        for (int j = 0; j < 8; ++j) pB[j] = *(const float4*)(uptr + (size_t)t * NS + j * 16);
    }

    // loop-invariant LDS offsets (verbatim state swizzle)
    int bfOff[4];
    #pragma unroll
    for (int kt = 0; kt < 4; ++kt) bfOff[kt] = bcol * NS + (((kt * 4 + quad) ^ bcol) << 3);
    const int s4Off = bcol * NS + (bcol << 3);    // logical chunk 0
    int fwo[8], euW[8];
    #pragma unroll
    for (int j = 0; j < 8; ++j) {
        const int cj = 2 * j + (quad >> 1);       // chunk of rows j*16+quad*4..+3
        fwo[j] = bcol * NS + ((cj ^ bcol) << 3) + ((quad & 1) << 2);
        euW[j] = bcol * NS + (((cj ^ bcol) & 15) << 3) + ((quad & 1) << 2);  // + n*2048
    }

    asm volatile("s_waitcnt lgkmcnt(0)" ::: "memory");   // init staging visible (same wave)
    float C = 0.f;

    // ======================= FWD sweep (stages EU) ==========================
#define STEP_F(U) do {                                                            \
    short8 Bf0 = *(const short8*)&Fs[bfOff[0]];                                   \
    short8 Bf1 = *(const short8*)&Fs[bfOff[1]];                                   \
    short8 Bf2 = *(const short8*)&Fs[bfOff[2]];                                   \
    short8 Bf3 = *(const short8*)&Fs[bfOff[3]];                                   \
    short4v s4 = *(const short4v*)&Fs[s4Off];                                     \
    float sv = (bf2f(s4[0]) + bf2f(s4[1])) + (bf2f(s4[2]) + bf2f(s4[3]));         \
    float rs = __fdividef(1.f, sv);                                               \
    float logs = __logf(sv);                                                      \
    f32x4 acc[8];                                                                 \
    _Pragma("unroll")                                                             \
    for (int j = 0; j < 8; ++j) acc[j] = (f32x4){0.f, 0.f, 0.f, 0.f};             \
    _Pragma("unroll")                                                             \
    for (int j = 0; j < 8; ++j) acc[j] = __builtin_amdgcn_mfma_f32_16x16x32_bf16(Ea[j][0], Bf0, acc[j], 0, 0, 0); \
    _Pragma("unroll")                                                             \
    for (int j = 0; j < 8; ++j) acc[j] = __builtin_amdgcn_mfma_f32_16x16x32_bf16(Ea[j][1], Bf1, acc[j], 0, 0, 0); \
    _Pragma("unroll")                                                             \
    for (int j = 0; j < 8; ++j) acc[j] = __builtin_amdgcn_mfma_f32_16x16x32_bf16(Ea[j][2], Bf2, acc[j], 0, 0, 0); \
    _Pragma("unroll")                                                             \
    for (int j = 0; j < 8; ++j) acc[j] = __builtin_amdgcn_mfma_f32_16x16x32_bf16(Ea[j][3], Bf3, acc[j], 0, 0, 0); \
    const int eub = n * (BT * NS);                                                \
    int t2 = T_F(n + 2);                                                          \
    _Pragma("unroll")                                                             \
    for (int j = 0; j < 8; ++j) {                                                 \
        float e0 = __expf(U[j].x), e1 = __expf(U[j].y);                           \
        float e2 = __expf(U[j].z), e3 = __expf(U[j].w);                           \
        short4v w;                                                                \
        w[0] = f2bf(e0); w[1] = f2bf(e1); w[2] = f2bf(e2); w[3] = f2bf(e3);       \
        *(short4v*)&EU[eub + euW[j]] = w;                                         \
        acc[j][0] *= e0 * rs; acc[j][1] *= e1 * rs;                               \
        acc[j][2] *= e2 * rs; acc[j][3] *= e3 * rs;                               \
        U[j] = *(const float4*)(uptr + (size_t)t2 * NS + j * 16);                 \
    }                                                                             \
    if (s < SEG - 1 && n == nrec) {   /* record normalized post-step + C_after */ \
        float* yp = yv + ((size_t)s * NB + g * BT + bcol) * NS;                   \
        _Pragma("unroll")                                                         \
        for (int j = 0; j < 8; ++j)                                               \
            *(float4*)(yp + j * 16 + quad * 4) = (float4){acc[j][0], acc[j][1], acc[j][2], acc[j][3]}; \
        if (tid < BT) cfv[s * NB + g * BT + tid] = C + logs;                      \
    }                                                                             \
    C += logs;                                                                    \
    _Pragma("unroll")                                                             \
    for (int j = 0; j < 8; ++j) {                                                 \
        short4v p;                                                                \
        p[0] = f2bf_trunc(acc[j][0]); p[1] = f2bf_trunc(acc[j][1]);               \
        p[2] = f2bf_trunc(acc[j][2]); p[3] = f2bf_trunc(acc[j][3]);               \
        *(short4v*)&Fs[fwo[j]] = p;                                               \
    }                                                                             \
    asm volatile("s_waitcnt lgkmcnt(0)" ::: "memory");                            \
} while (0)

    for (int n = 0; n < iters; ) {
        STEP_F(pA); ++n;
        if (n >= iters) break;
        STEP_F(pB); ++n;
    }
#undef STEP_F
#undef T_F

    // ======================= BWD sweep (reads EU) ===========================
    if (s != 0) {
        if (iters > 0) {
            // rebuild A-fragments as E^T
            #pragma unroll
            for (int j = 0; j < 8; ++j) {
                const int i = j * 16 + bcol;
                #pragma unroll
                for (int kt = 0; kt < 4; ++kt) {
                    short8 e;
                    #pragma unroll
                    for (int jj = 0; jj < 8; ++jj)
                        e[jj] = f2bf(__expf(trans[(size_t)(kt * 32 + quad * 8 + jj) * NS + i]));
                    Ea[j][kt] = e;
                }
            }
        }
        // bwd init: q = eu_{te-1} (*) v  (eu from EU ring) + empty records
        #pragma unroll
        for (int rep = 0; rep < 4; ++rep) {
            const int tv = rep * 64 + tid;
            const int sr = tv >> 4, sc = tv & 15;
            const int Ls = lengths[g * BT + sr];
            const int s_tb = (s * Ls) >> SSH, s_te = ((s + 1) * Ls) >> SSH;
            const int sl = s_te - s_tb;
            if (sl == 0) {        // empty: identity bridge, seed v = ones
                float* zp = zv + ((size_t)(s - 1) * NB + g * BT + sr) * NS + sc * 8;
                #pragma unroll
                for (int k = 0; k < 8; ++k) zp[k] = 1.f;
                if (sc == 0) cbv[(s - 1) * NB + g * BT + sr] = 0.f;
                // seed state = ones (finite; never recorded)
                short8 z;
                #pragma unroll
                for (int k = 0; k < 8; ++k) z[k] = f2bf(1.f);
                *(short8*)&Fs[sr * NS + ((sc ^ sr) << 3)] = z;
            } else {
                const int r0 = sl - 1;
                short8 eu8 = *(const short8*)&EU[r0 * (BT * NS) + sr * NS + (((sc ^ sr) & 15) << 3)];
                short8 z;
                #pragma unroll
                for (int k = 0; k < 8; ++k) {
                    float vv = (s == SEG - 1) ? __expf(trans[2 * NS + sc * 8 + k]) : 1.f;
                    z[k] = f2bf(bf2f(eu8[k]) * vv);
                }
                *(short8*)&Fs[sr * NS + ((sc ^ sr) << 3)] = z;
            }
        }

        if (iters > 0) {
            asm volatile("s_waitcnt lgkmcnt(0)" ::: "memory");
            float Cb = 0.f;
            for (int m = 0; m < iters; ++m) {
                short8 Bf0 = *(const short8*)&Fs[bfOff[0]];
                short8 Bf1 = *(const short8*)&Fs[bfOff[1]];
                short8 Bf2 = *(const short8*)&Fs[bfOff[2]];
                short8 Bf3 = *(const short8*)&Fs[bfOff[3]];
                short4v s4 = *(const short4v*)&Fs[s4Off];
                float sv = (bf2f(s4[0]) + bf2f(s4[1])) + (bf2f(s4[2]) + bf2f(s4[3]));
                float rs = __fdividef(1.f, sv);
                float logs = __logf(sv);
                f32x4 acc[8];
                #pragma unroll
                for (int j = 0; j < 8; ++j) acc[j] = (f32x4){0.f, 0.f, 0.f, 0.f};
                #pragma unroll
                for (int j = 0; j < 8; ++j) acc[j] = __builtin_amdgcn_mfma_f32_16x16x32_bf16(Ea[j][0], Bf0, acc[j], 0, 0, 0);
                #pragma unroll
                for (int j = 0; j < 8; ++j) acc[j] = __builtin_amdgcn_mfma_f32_16x16x32_bf16(Ea[j][1], Bf1, acc[j], 0, 0, 0);
                #pragma unroll
                for (int j = 0; j < 8; ++j) acc[j] = __builtin_amdgcn_mfma_f32_16x16x32_bf16(Ea[j][2], Bf2, acc[j], 0, 0, 0);
                #pragma unroll
                for (int j = 0; j < 8; ++j) acc[j] = __builtin_amdgcn_mfma_f32_16x16x32_bf16(Ea[j][3], Bf3, acc[j], 0, 0, 0);

                if (m == nrec) {  // record RAW acc = E^T q (pre-eu) + C_before
                    float* zp = zv + ((size_t)(s - 1) * NB + g * BT + bcol) * NS;
                    #pragma unroll
                    for (int j = 0; j < 8; ++j)
                        *(float4*)(zp + j * 16 + quad * 4) = (float4){acc[j][0], acc[j][1], acc[j][2], acc[j][3]};
                    if (tid < BT) cbv[(s - 1) * NB + g * BT + tid] = Cb;
                }

                int r = slen - 2 - m; r = r < 0 ? 0 : r;   // per-batch (lane) row
                const int rb = r * (BT * NS);
                #pragma unroll
                for (int j = 0; j < 8; ++j) {
                    short4v ev = *(const short4v*)&EU[rb + euW[j]];
                    acc[j][0] *= bf2f(ev[0]) * rs; acc[j][1] *= bf2f(ev[1]) * rs;
                    acc[j][2] *= bf2f(ev[2]) * rs; acc[j][3] *= bf2f(ev[3]) * rs;
                }
                Cb += logs;

                #pragma unroll
                for (int j = 0; j < 8; ++j) {
                    short4v p;
                    p[0] = f2bf_trunc(acc[j][0]); p[1] = f2bf_trunc(acc[j][1]);
                    p[2] = f2bf_trunc(acc[j][2]); p[3] = f2bf_trunc(acc[j][3]);
                    *(short4v*)&Fs[fwo[j]] = p;
                }
                asm volatile("s_waitcnt lgkmcnt(0)" ::: "memory");
            }
        }
    }
}

// out = Cf_0 + sum_{s=1..S-1} Cb_s + sum_{s=1..S-1} log(Z_s . Y_{s-1})
//       - sum_{s=1..S-2} log sum(Y_s)
// 4 waves split the s-range (strided); deterministic LDS combine.
__global__ __launch_bounds__(256) void crf_combine(
        const float* __restrict__ yv, const float* __restrict__ zv,
        const float* __restrict__ cfv, const float* __restrict__ cbv,
        float* __restrict__ out) {
    __shared__ float part[4];
    const int b = blockIdx.x, tid = threadIdx.x;
    const int w = tid >> 6, lane = tid & 63;
    float lg = 0.f;
    for (int s = 1 + w; s <= SEG - 1; s += 4) lg += cbv[(s - 1) * NB + b];
    for (int s = 1 + w; s <= SEG - 1; s += 4) {
        const float* Z = zv + ((size_t)(s - 1) * NB + b) * NS;
        const float* Y = yv + ((size_t)(s - 1) * NB + b) * NS;
        float d = Z[lane] * Y[lane] + Z[lane + 64] * Y[lane + 64];
        #pragma unroll
        for (int off = 1; off < 64; off <<= 1) d += __shfl_xor(d, off, 64);
        lg += __logf(d);
    }
    for (int s = 1 + w; s <= SEG - 2; s += 4) {
        const float* Y = yv + ((size_t)s * NB + b) * NS;
        float t = Y[lane] + Y[lane + 64];
        #pragma unroll
        for (int off = 1; off < 64; off <<= 1) t += __shfl_xor(t, off, 64);
        lg -= __logf(t);
    }
    if (lane == 0) part[w] = lg;
    __syncthreads();
    if (tid == 0) out[b] = cfv[b] + ((part[0] + part[1]) + (part[2] + part[3]));
}

extern "C" void kernel_launch(void* const* d_in, const int* in_sizes, int n_in,
                              void* d_out, int out_size, void* d_ws, size_t ws_size,
                              hipStream_t stream) {
    const float* unary   = (const float*)d_in[0];
    const float* trans   = (const float*)d_in[1];
    const int*   lengths = (const int*)d_in[2];
    float* out = (float*)d_out;

    float* yv  = (float*)d_ws;                          // [S-1][NB][NS]
    float* zv  = yv + (size_t)(SEG - 1) * NB * NS;      // [S-1][NB][NS]
    float* cfv = zv + (size_t)(SEG - 1) * NB * NS;      // [S-1][NB]
    float* cbv = cfv + (size_t)(SEG - 1) * NB;          // [S-1][NB]

    crf_seg<<<dim3(SEG * G), dim3(64), 0, stream>>>(
        unary, trans, lengths, yv, zv, cfv, cbv);
    crf_combine<<<dim3(NB), dim3(256), 0, stream>>>(yv, zv, cfv, cbv, out);
}

// Round 7
// 253.748 us; speedup vs baseline: 1.0629x; 1.0629x over previous
//
#include <hip/hip_runtime.h>

#define T_LEN 1024
#define NS    128
#define BT    16
#define G     16
#define SEG   128        // time segments per sequence (power of 2)
#define SSH   7          // log2(SEG)
#define ST    8          // max rows per segment = T_LEN/SEG
#define NB    256        // total batches

typedef __attribute__((ext_vector_type(8))) short short8;
typedef __attribute__((ext_vector_type(4))) short short4v;
typedef __attribute__((ext_vector_type(4))) float f32x4;

static __device__ __forceinline__ short f2bf(float f) {   // RNE
    unsigned u = __builtin_bit_cast(unsigned, f);
    u = (u + 0x7fffu + ((u >> 16) & 1u)) >> 16;
    return (short)u;
}
static __device__ __forceinline__ float bf2f(short s) {
    unsigned u = ((unsigned)(unsigned short)s) << 16;
    return __builtin_bit_cast(float, u);
}
static __device__ __forceinline__ short f2bf_trunc(float f) {  // in-loop: 1 op
    return (short)(__builtin_bit_cast(unsigned, f) >> 16);
}

// Segmented CRF forward, merged fwd+bwd per (s,g) block — 4-WAVE edition.
// (Resubmission of R6: container infra failure, no result.  Hardened: fwd EU
// reads past a batch's own slen are clamped to its last valid row — avoids
// 0*inf NaN in dead columns; otherwise identical.)
// Evidence R0-R5: only waves/CU ever moved crf_seg (4-wave 15.5w/CU = 66us vs
// 1-wave = 85-95us); iters/bytes/granularity all null.  Keeps R5's fetch-once
// EU (exp(unary) staged bf16 in LDS, read by BOTH sweeps) but:
//  (1) 256-thread 4-wave blocks, R1's verified step split (wave w owns rows
//      [w*32,w*32+32)), 16 waves/CU residency (36.9KB LDS -> 4 blocks/CU).
//  (2) prologue SLAB-LOAD: each batch's segment is read as one contiguous
//      ~4KB run (16 coalesced dwordx4-pair chunks, deep MLP) -> page-friendly
//      streaming, each unary row fetched exactly once.
//  (3) steps are LDS-only (no per-step global traffic, no per-step exp).
// EU swizzle = Fs swizzle family, so e-read offsets == fw0/fw1 + row*2048.
// Single-buffer Fs with two lgkm+barrier per step (read-set | write-set).
__global__ __launch_bounds__(256, 4) void crf_seg(
        const float* __restrict__ unary, const float* __restrict__ trans,
        const int* __restrict__ lengths,
        float* __restrict__ yv, float* __restrict__ zv,
        float* __restrict__ cfv, float* __restrict__ cbv) {
    __shared__ __align__(16) short Fs[BT * NS];        // 4KB bf16 state
    __shared__ __align__(16) short EU[ST * BT * NS];   // 32KB bf16 exp(unary)
    __shared__ int tbS[BT], teS[BT];

    const int tid = threadIdx.x;                  // 0..255 (4 waves)
    const int g = blockIdx.x & (G - 1);
    const int s = blockIdx.x >> 4;                // 0..SEG-1
    const int w = tid >> 6, lane = tid & 63;
    const int quad = lane >> 4, bcol = lane & 15;

    if (tid < BT) {
        int L = lengths[g * BT + tid];
        tbS[tid] = (s * L) >> SSH;
        teS[tid] = ((s + 1) * L) >> SSH;
    }
    // zero EU (row 0 of never-loaded batches stays finite-zero)
    {
        short8 z = {0, 0, 0, 0, 0, 0, 0, 0};
        #pragma unroll
        for (int k = 0; k < 8; ++k) *(short8*)&EU[tid * 64 + k * 8] = z;
    }
    __syncthreads();

    const int tb = tbS[bcol], te = teS[bcol];
    const int slen = te - tb;
    const int nrec = slen - 1;                    // -1 => record happened at init
    int iters = 0;
    #pragma unroll
    for (int b = 0; b < BT; ++b) {
        int d = teS[b] - tbS[b];
        iters = d > iters ? d : iters;
    }
    const int slc = slen > 0 ? slen - 1 : 0;      // per-batch clamp row

    // ---- prologue slab-load: thread -> (batch sb, row rr, half hh) ----
    // per batch the segment is CONTIGUOUS (slen x 512B); 16 threads/batch read
    // it as dense 256B chunks -> streaming bursts, each row fetched once.
    {
        const int sb = tid >> 4, rr = (tid >> 1) & 7, hh = tid & 1;
        const int sl = teS[sb] - tbS[sb];
        if (rr < sl) {
            const float* src = unary + ((size_t)(g * BT + sb) * T_LEN + tbS[sb] + rr) * NS + hh * 64;
            #pragma unroll
            for (int k8 = 0; k8 < 8; ++k8) {
                float4 x = *(const float4*)(src + k8 * 8);
                float4 y = *(const float4*)(src + k8 * 8 + 4);
                short8 e;
                e[0] = f2bf(__expf(x.x)); e[1] = f2bf(__expf(x.y));
                e[2] = f2bf(__expf(x.z)); e[3] = f2bf(__expf(x.w));
                e[4] = f2bf(__expf(y.x)); e[5] = f2bf(__expf(y.y));
                e[6] = f2bf(__expf(y.z)); e[7] = f2bf(__expf(y.w));
                const int c8 = hh * 8 + k8;
                *(short8*)&EU[rr * (BT * NS) + sb * NS + (((c8 ^ sb) & 15) << 3)] = e;
            }
        }
    }

    // ---- A-fragments: E (fwd), wave w's rows only (R1 mapping) ----
    short8 Ea[2][4];
    if (s < SEG - 1) {
        #pragma unroll
        for (int mt = 0; mt < 2; ++mt) {
            const int i = w * 32 + mt * 16 + bcol;
            #pragma unroll
            for (int kt = 0; kt < 4; ++kt) {
                const float* tr = trans + (size_t)i * NS + kt * 32 + quad * 8;
                float4 x = *(const float4*)tr, y = *(const float4*)(tr + 4);
                short8 e;
                e[0] = f2bf(__expf(x.x)); e[1] = f2bf(__expf(x.y));
                e[2] = f2bf(__expf(x.z)); e[3] = f2bf(__expf(x.w));
                e[4] = f2bf(__expf(y.x)); e[5] = f2bf(__expf(y.y));
                e[6] = f2bf(__expf(y.z)); e[7] = f2bf(__expf(y.w));
                Ea[mt][kt] = e;
            }
        }
    }

    // ---- fwd init state into Fs + fwd empty-segment records ----
    {
        const int sr = tid >> 4, sc = tid & 15;
        const int sl = teS[sr] - tbS[sr];
        short8 z;
        #pragma unroll
        for (int k = 0; k < 8; ++k)
            z[k] = f2bf((s == 0) ? ((sc * 8 + k == 1) ? 1.f : 0.f) : 1.f);
        *(short8*)&Fs[sr * NS + ((sc ^ sr) << 3)] = z;

        if (sl == 0 && s < SEG - 1) {             // empty: record fwd seed
            float* yp = yv + ((size_t)s * NB + g * BT + sr) * NS + sc * 8;
            #pragma unroll
            for (int k = 0; k < 8; ++k)
                yp[k] = (s == 0) ? ((sc * 8 + k == 1) ? 1.f : 0.f) : 1.f;
            if (sc == 0) cfv[s * NB + g * BT + sr] = 0.f;
        }
    }
    __syncthreads();

    // loop-invariant LDS offsets (verbatim R1 swizzle; EU mirrors Fs layout)
    int bfOff[4];
    #pragma unroll
    for (int kt = 0; kt < 4; ++kt) bfOff[kt] = bcol * NS + (((kt * 4 + quad) ^ bcol) << 3);
    const int s4Off = bcol * NS + (bcol << 3);
    const int c0 = w * 4 + (quad >> 1), halfo = (quad & 1) << 2;
    const int fw0 = bcol * NS + ((c0 ^ bcol) << 3) + halfo;
    const int fw1 = bcol * NS + (((c0 + 2) ^ bcol) << 3) + halfo;
    // e-read offsets: EU granule == Fs granule, + row*(BT*NS)

#define LGKM_BAR() do { asm volatile("s_waitcnt lgkmcnt(0)" ::: "memory"); \
                        __builtin_amdgcn_s_barrier(); } while (0)

    // ======================= FWD sweep ==========================
    if (s < SEG - 1) {
        float C = 0.f;
        for (int n = 0; n < iters; ++n) {
            short8 Bf0 = *(const short8*)&Fs[bfOff[0]];
            short8 Bf1 = *(const short8*)&Fs[bfOff[1]];
            short8 Bf2 = *(const short8*)&Fs[bfOff[2]];
            short8 Bf3 = *(const short8*)&Fs[bfOff[3]];
            short4v s4 = *(const short4v*)&Fs[s4Off];
            const int er = n < slen ? n : slc;     // own-row clamp (finite columns)
            short4v ev0 = *(const short4v*)&EU[er * (BT * NS) + fw0];
            short4v ev1 = *(const short4v*)&EU[er * (BT * NS) + fw1];
            LGKM_BAR();                            // read-set complete before writes

            float sv = (bf2f(s4[0]) + bf2f(s4[1])) + (bf2f(s4[2]) + bf2f(s4[3]));
            float rs = __fdividef(1.f, sv);
            float logs = __logf(sv);

            f32x4 x0 = {0.f,0.f,0.f,0.f}, y0 = {0.f,0.f,0.f,0.f};
            f32x4 x1 = {0.f,0.f,0.f,0.f}, y1 = {0.f,0.f,0.f,0.f};
            x0 = __builtin_amdgcn_mfma_f32_16x16x32_bf16(Ea[0][0], Bf0, x0, 0, 0, 0);
            x1 = __builtin_amdgcn_mfma_f32_16x16x32_bf16(Ea[1][0], Bf0, x1, 0, 0, 0);
            y0 = __builtin_amdgcn_mfma_f32_16x16x32_bf16(Ea[0][2], Bf2, y0, 0, 0, 0);
            y1 = __builtin_amdgcn_mfma_f32_16x16x32_bf16(Ea[1][2], Bf2, y1, 0, 0, 0);
            x0 = __builtin_amdgcn_mfma_f32_16x16x32_bf16(Ea[0][1], Bf1, x0, 0, 0, 0);
            x1 = __builtin_amdgcn_mfma_f32_16x16x32_bf16(Ea[1][1], Bf1, x1, 0, 0, 0);
            y0 = __builtin_amdgcn_mfma_f32_16x16x32_bf16(Ea[0][3], Bf3, y0, 0, 0, 0);
            y1 = __builtin_amdgcn_mfma_f32_16x16x32_bf16(Ea[1][3], Bf3, y1, 0, 0, 0);
            f32x4 a0 = x0 + y0, a1 = x1 + y1;

            float fn0[4], fn1[4];
            #pragma unroll
            for (int r = 0; r < 4; ++r) {
                fn0[r] = a0[r] * bf2f(ev0[r]) * rs;
                fn1[r] = a1[r] * bf2f(ev1[r]) * rs;
            }

            if (n == nrec) {   // record normalized post-step state + C_after
                float* yp = yv + ((size_t)s * NB + g * BT + bcol) * NS;
                *(float4*)(yp + w * 32 + quad * 4)      = (float4){fn0[0], fn0[1], fn0[2], fn0[3]};
                *(float4*)(yp + w * 32 + 16 + quad * 4) = (float4){fn1[0], fn1[1], fn1[2], fn1[3]};
                if (tid < BT) cfv[s * NB + g * BT + tid] = C + logs;
            }
            C += logs;

            short4v p0, p1;
            #pragma unroll
            for (int r = 0; r < 4; ++r) { p0[r] = f2bf_trunc(fn0[r]); p1[r] = f2bf_trunc(fn1[r]); }
            *(short4v*)&Fs[fw0] = p0;
            *(short4v*)&Fs[fw1] = p1;
            LGKM_BAR();                            // write-set visible for next read
        }
    }

    // ======================= BWD sweep ==========================
    if (s != 0) {
        if (iters > 0) {
            #pragma unroll
            for (int mt = 0; mt < 2; ++mt) {       // rebuild as E^T (wave's rows)
                const int i = w * 32 + mt * 16 + bcol;
                #pragma unroll
                for (int kt = 0; kt < 4; ++kt) {
                    short8 e;
                    #pragma unroll
                    for (int jj = 0; jj < 8; ++jj)
                        e[jj] = f2bf(__expf(trans[(size_t)(kt * 32 + quad * 8 + jj) * NS + i]));
                    Ea[mt][kt] = e;
                }
            }
        }
        // bwd init: q = eu_{te-1} (*) v  (eu from EU) + empty records
        {
            const int sr = tid >> 4, sc = tid & 15;
            const int sl = teS[sr] - tbS[sr];
            if (sl == 0) {        // empty: identity bridge, seed v = ones
                float* zp = zv + ((size_t)(s - 1) * NB + g * BT + sr) * NS + sc * 8;
                #pragma unroll
                for (int k = 0; k < 8; ++k) zp[k] = 1.f;
                if (sc == 0) cbv[(s - 1) * NB + g * BT + sr] = 0.f;
                short8 z;
                #pragma unroll
                for (int k = 0; k < 8; ++k) z[k] = f2bf(1.f);
                *(short8*)&Fs[sr * NS + ((sc ^ sr) << 3)] = z;
            } else {
                short8 eu8 = *(const short8*)&EU[(sl - 1) * (BT * NS) + sr * NS + (((sc ^ sr) & 15) << 3)];
                short8 z;
                #pragma unroll
                for (int k = 0; k < 8; ++k) {
                    float vv = (s == SEG - 1) ? __expf(trans[2 * NS + sc * 8 + k]) : 1.f;
                    z[k] = f2bf(bf2f(eu8[k]) * vv);
                }
                *(short8*)&Fs[sr * NS + ((sc ^ sr) << 3)] = z;
            }
        }
        __syncthreads();

        float Cb = 0.f;
        for (int m = 0; m < iters; ++m) {
            short8 Bf0 = *(const short8*)&Fs[bfOff[0]];
            short8 Bf1 = *(const short8*)&Fs[bfOff[1]];
            short8 Bf2 = *(const short8*)&Fs[bfOff[2]];
            short8 Bf3 = *(const short8*)&Fs[bfOff[3]];
            short4v s4 = *(const short4v*)&Fs[s4Off];
            int r = slen - 2 - m; r = r < 0 ? 0 : r;          // per-batch row
            short4v ev0 = *(const short4v*)&EU[r * (BT * NS) + fw0];
            short4v ev1 = *(const short4v*)&EU[r * (BT * NS) + fw1];
            LGKM_BAR();

            float sv = (bf2f(s4[0]) + bf2f(s4[1])) + (bf2f(s4[2]) + bf2f(s4[3]));
            float rs = __fdividef(1.f, sv);
            float logs = __logf(sv);

            f32x4 x0 = {0.f,0.f,0.f,0.f}, y0 = {0.f,0.f,0.f,0.f};
            f32x4 x1 = {0.f,0.f,0.f,0.f}, y1 = {0.f,0.f,0.f,0.f};
            x0 = __builtin_amdgcn_mfma_f32_16x16x32_bf16(Ea[0][0], Bf0, x0, 0, 0, 0);
            x1 = __builtin_amdgcn_mfma_f32_16x16x32_bf16(Ea[1][0], Bf0, x1, 0, 0, 0);
            y0 = __builtin_amdgcn_mfma_f32_16x16x32_bf16(Ea[0][2], Bf2, y0, 0, 0, 0);
            y1 = __builtin_amdgcn_mfma_f32_16x16x32_bf16(Ea[1][2], Bf2, y1, 0, 0, 0);
            x0 = __builtin_amdgcn_mfma_f32_16x16x32_bf16(Ea[0][1], Bf1, x0, 0, 0, 0);
            x1 = __builtin_amdgcn_mfma_f32_16x16x32_bf16(Ea[1][1], Bf1, x1, 0, 0, 0);
            y0 = __builtin_amdgcn_mfma_f32_16x16x32_bf16(Ea[0][3], Bf3, y0, 0, 0, 0);
            y1 = __builtin_amdgcn_mfma_f32_16x16x32_bf16(Ea[1][3], Bf3, y1, 0, 0, 0);
            f32x4 a0 = x0 + y0, a1 = x1 + y1;

            if (m == nrec) {  // record RAW acc = E^T q (pre-eu) + C_before
                float* zp = zv + ((size_t)(s - 1) * NB + g * BT + bcol) * NS;
                *(float4*)(zp + w * 32 + quad * 4)      = (float4){a0[0], a0[1], a0[2], a0[3]};
                *(float4*)(zp + w * 32 + 16 + quad * 4) = (float4){a1[0], a1[1], a1[2], a1[3]};
                if (tid < BT) cbv[(s - 1) * NB + g * BT + tid] = Cb;
            }

            float fn0[4], fn1[4];
            #pragma unroll
            for (int r2 = 0; r2 < 4; ++r2) {
                fn0[r2] = a0[r2] * bf2f(ev0[r2]) * rs;
                fn1[r2] = a1[r2] * bf2f(ev1[r2]) * rs;
            }
            Cb += logs;

            short4v p0, p1;
            #pragma unroll
            for (int r2 = 0; r2 < 4; ++r2) { p0[r2] = f2bf_trunc(fn0[r2]); p1[r2] = f2bf_trunc(fn1[r2]); }
            *(short4v*)&Fs[fw0] = p0;
            *(short4v*)&Fs[fw1] = p1;
            LGKM_BAR();
        }
    }
#undef LGKM_BAR
}

// out = Cf_0 + sum_{s=1..S-1} Cb_s + sum_{s=1..S-1} log(Z_s . Y_{s-1})
//       - sum_{s=1..S-2} log sum(Y_s)
// 4 waves split the s-range (strided); deterministic LDS combine.
__global__ __launch_bounds__(256) void crf_combine(
        const float* __restrict__ yv, const float* __restrict__ zv,
        const float* __restrict__ cfv, const float* __restrict__ cbv,
        float* __restrict__ out) {
    __shared__ float part[4];
    const int b = blockIdx.x, tid = threadIdx.x;
    const int w = tid >> 6, lane = tid & 63;
    float lg = 0.f;
    for (int s = 1 + w; s <= SEG - 1; s += 4) lg += cbv[(s - 1) * NB + b];
    for (int s = 1 + w; s <= SEG - 1; s += 4) {
        const float* Z = zv + ((size_t)(s - 1) * NB + b) * NS;
        const float* Y = yv + ((size_t)(s - 1) * NB + b) * NS;
        float d = Z[lane] * Y[lane] + Z[lane + 64] * Y[lane + 64];
        #pragma unroll
        for (int off = 1; off < 64; off <<= 1) d += __shfl_xor(d, off, 64);
        lg += __logf(d);
    }
    for (int s = 1 + w; s <= SEG - 2; s += 4) {
        const float* Y = yv + ((size_t)s * NB + b) * NS;
        float t = Y[lane] + Y[lane + 64];
        #pragma unroll
        for (int off = 1; off < 64; off <<= 1) t += __shfl_xor(t, off, 64);
        lg -= __logf(t);
    }
    if (lane == 0) part[w] = lg;
    __syncthreads();
    if (tid == 0) out[b] = cfv[b] + ((part[0] + part[1]) + (part[2] + part[3]));
}

extern "C" void kernel_launch(void* const* d_in, const int* in_sizes, int n_in,
                              void* d_out, int out_size, void* d_ws, size_t ws_size,
                              hipStream_t stream) {
    const float* unary   = (const float*)d_in[0];
    const float* trans   = (const float*)d_in[1];
    const int*   lengths = (const int*)d_in[2];
    float* out = (float*)d_out;

    float* yv  = (float*)d_ws;                          // [S-1][NB][NS]
    float* zv  = yv + (size_t)(SEG - 1) * NB * NS;      // [S-1][NB][NS]
    float* cfv = zv + (size_t)(SEG - 1) * NB * NS;      // [S-1][NB]
    float* cbv = cfv + (size_t)(SEG - 1) * NB;          // [S-1][NB]

    crf_seg<<<dim3(SEG * G), dim3(256), 0, stream>>>(
        unary, trans, lengths, yv, zv, cfv, cbv);
    crf_combine<<<dim3(NB), dim3(256), 0, stream>>>(yv, zv, cfv, cbv, out);
}